// Round 7
// baseline (289.816 us; speedup 1.0000x reference)
//
#include <hip/hip_runtime.h>
#include <stdint.h>
#include <math.h>

#define NB 24
#define NC 128
#define NH 8
#define NDK 16
#define NL 512
#define NTOT (24*128*512)

// ---------------- threefry2x32 (JAX-compatible) ----------------
__host__ __device__ inline void tf2x32(uint32_t k0, uint32_t k1, uint32_t& x0, uint32_t& x1) {
  uint32_t ks2 = k0 ^ k1 ^ 0x1BD11BDAu;
  x0 += k0; x1 += k1;
#define TF_R(r) { x0 += x1; x1 = (x1 << r) | (x1 >> (32 - r)); x1 ^= x0; }
  TF_R(13) TF_R(15) TF_R(26) TF_R(6)
  x0 += k1;  x1 += ks2 + 1u;
  TF_R(17) TF_R(29) TF_R(16) TF_R(24)
  x0 += ks2; x1 += k0 + 2u;
  TF_R(13) TF_R(15) TF_R(26) TF_R(6)
  x0 += k0;  x1 += k1 + 3u;
  TF_R(17) TF_R(29) TF_R(16) TF_R(24)
  x0 += k1;  x1 += ks2 + 4u;
  TF_R(13) TF_R(15) TF_R(26) TF_R(6)
  x0 += ks2; x1 += k0 + 5u;
#undef TF_R
}

__device__ inline float drop_scale(uint32_t k0, uint32_t k1, uint32_t idx) {
  uint32_t x0 = 0u, x1 = idx;
  tf2x32(k0, k1, x0, x1);
  uint32_t bits = x0 ^ x1;
  float u = __uint_as_float((bits >> 9) | 0x3f800000u) - 1.0f;
  return (u < 0.9f) ? (1.0f / 0.9f) : 0.0f;
}

// ---------------- positional encoding + add ----------------
__global__ __launch_bounds__(256) void pos_add_kernel(const float* __restrict__ x,
                                                      float* __restrict__ out) {
  int idx = blockIdx.x * 256 + threadIdx.x;
  int l = idx & (NL - 1);
  int c = (idx >> 9) & (NC - 1);
  int ce = c & ~1;
  double base = exp(-(double)ce * 9.210340371976184 / 128.0); // ln(10000)
  float freq = (c & 1) ? -(float)base : (float)base;
  float phase = (c & 1) ? (float)(M_PI / 2.0) : 0.0f;
  float pe = sinf(sinf((float)l * freq + phase));
  out[idx] = x[idx] + pe;
}

// ---------------- fused layernorm (+ optional depthwise conv) ----------------
template<bool DO_CONV>
__global__ __launch_bounds__(64) void norm_dw_kernel(const float* __restrict__ in,
                                                     float* __restrict__ outp,
                                                     const float* __restrict__ dww,
                                                     const float* __restrict__ dwb) {
  int row = blockIdx.x;           // b*NC + c
  int c = row & (NC - 1);
  int t = threadIdx.x;
  const float* rp = in + (size_t)row * NL;
  float4 v0 = ((const float4*)rp)[t * 2];
  float4 v1 = ((const float4*)rp)[t * 2 + 1];
  float xr[8] = {v0.x, v0.y, v0.z, v0.w, v1.x, v1.y, v1.z, v1.w};
  float s = 0.f;
#pragma unroll
  for (int j = 0; j < 8; ++j) s += xr[j];
#pragma unroll
  for (int off = 32; off >= 1; off >>= 1) s += __shfl_xor(s, off);
  float mean = s * (1.0f / 512.0f);
  float sq = 0.f;
#pragma unroll
  for (int j = 0; j < 8; ++j) { xr[j] -= mean; sq += xr[j] * xr[j]; }
#pragma unroll
  for (int off = 32; off >= 1; off >>= 1) sq += __shfl_xor(sq, off);
  float inv = 1.0f / (sqrtf(sq * (1.0f / 511.0f)) + 1e-6f);

  if (!DO_CONV) {
    float4 o0 = make_float4(xr[0]*inv, xr[1]*inv, xr[2]*inv, xr[3]*inv);
    float4 o1 = make_float4(xr[4]*inv, xr[5]*inv, xr[6]*inv, xr[7]*inv);
    float4* op = (float4*)(outp + (size_t)row * NL);
    op[t * 2] = o0; op[t * 2 + 1] = o1;
  } else {
    __shared__ float rb[NL + 6];
    if (t < 3) { rb[t] = 0.f; rb[NL + 3 + t] = 0.f; }
#pragma unroll
    for (int j = 0; j < 8; ++j) rb[3 + t * 8 + j] = xr[j] * inv;
    __syncthreads();
    float w[7];
#pragma unroll
    for (int u = 0; u < 7; ++u) w[u] = dww[c * 7 + u];
    float bias = dwb[c];
    float* op = outp + (size_t)row * NL + t * 8;
#pragma unroll
    for (int j = 0; j < 8; ++j) {
      int l = t * 8 + j;
      float o = bias;
#pragma unroll
      for (int u = 0; u < 7; ++u) o += rb[l + u] * w[u];
      op[j] = o;
    }
  }
}

// ---------------- per-batch 128x128 @ 128x512 GEMM with fused epilogues ----------------
template<int EPI, bool A_PER_B>
__global__ __launch_bounds__(256) void gemm128_kernel(const float* __restrict__ A,
                                                      const float* __restrict__ X,
                                                      float* __restrict__ Y,
                                                      const float* __restrict__ bias,
                                                      const float* __restrict__ resid,
                                                      uint32_t k0, uint32_t k1) {
  __shared__ float As[64][129];
  __shared__ float Xs[128][68];
  int b  = blockIdx.z;
  int m0 = blockIdx.y * 64;
  int l0 = blockIdx.x * 64;
  int t  = threadIdx.x;
  const float* Ab = A + (A_PER_B ? (size_t)b * NC * NC : 0);
  const float* Xb = X + (size_t)b * NC * NL;

#pragma unroll
  for (int i = 0; i < 8; ++i) {
    int id = t + i * 256;
    int r = id >> 5;
    int c4 = (id & 31) << 2;
    float4 v = *(const float4*)&Ab[(size_t)(m0 + r) * NC + c4];
    As[r][c4] = v.x; As[r][c4+1] = v.y; As[r][c4+2] = v.z; As[r][c4+3] = v.w;
  }
#pragma unroll
  for (int i = 0; i < 8; ++i) {
    int id = t + i * 256;
    int r = id >> 4;
    int c4 = (id & 15) << 2;
    float4 v = *(const float4*)&Xb[(size_t)r * NL + l0 + c4];
    Xs[r][c4] = v.x; Xs[r][c4+1] = v.y; Xs[r][c4+2] = v.z; Xs[r][c4+3] = v.w;
  }
  __syncthreads();

  int tm = t >> 4, tl = t & 15;
  float acc[4][4] = {};
#pragma unroll 4
  for (int k = 0; k < 128; ++k) {
    float a0 = As[tm*4+0][k], a1 = As[tm*4+1][k], a2 = As[tm*4+2][k], a3 = As[tm*4+3][k];
    float4 xv = *(const float4*)&Xs[k][tl << 2];
    acc[0][0] += a0*xv.x; acc[0][1] += a0*xv.y; acc[0][2] += a0*xv.z; acc[0][3] += a0*xv.w;
    acc[1][0] += a1*xv.x; acc[1][1] += a1*xv.y; acc[1][2] += a1*xv.z; acc[1][3] += a1*xv.w;
    acc[2][0] += a2*xv.x; acc[2][1] += a2*xv.y; acc[2][2] += a2*xv.z; acc[2][3] += a2*xv.w;
    acc[3][0] += a3*xv.x; acc[3][1] += a3*xv.y; acc[3][2] += a3*xv.z; acc[3][3] += a3*xv.w;
  }

#pragma unroll
  for (int i = 0; i < 4; ++i) {
    int m = m0 + tm * 4 + i;
    float bv = (EPI == 0) ? bias[m] : 0.0f;
#pragma unroll
    for (int j = 0; j < 4; ++j) {
      int l = l0 + tl * 4 + j;
      float val = acc[i][j] + bv;
      if (EPI == 0 || EPI == 2) val = fmaxf(val, 0.0f);
      size_t idx = ((size_t)b * NC + m) * NL + l;
      float v2 = resid[idx] + val;
      float ds = drop_scale(k0, k1, (uint32_t)idx);
      Y[idx] = (ds == 0.0f) ? 0.0f : (v2 / 0.9f);
    }
  }
}

// ---------------- stacked QKV projection ----------------
__global__ __launch_bounds__(256) void qkv_kernel(const float* __restrict__ Wq,
                                                  const float* __restrict__ Wk,
                                                  const float* __restrict__ Wv,
                                                  const float* __restrict__ X,
                                                  float* __restrict__ out) {
  __shared__ float As[64][129];
  __shared__ float Xs[128][68];
  int b  = blockIdx.z;
  int m0 = blockIdx.y * 64;
  int l0 = blockIdx.x * 64;
  int t  = threadIdx.x;
  const float* Xb = X + (size_t)b * NC * NL;

#pragma unroll
  for (int i = 0; i < 8; ++i) {
    int id = t + i * 256;
    int r = id >> 5;
    int c4 = (id & 31) << 2;
    int gr = m0 + r;
    int sel = gr >> 7, w = gr & 127, h = w >> 4, kk = w & 15;
    const float* Wp = (sel == 0) ? Wq : ((sel == 1) ? Wk : Wv);
    const float* rowp = Wp + (((size_t)h * NB + b) * NDK + kk) * NC;
    float4 v = *(const float4*)&rowp[c4];
    As[r][c4] = v.x; As[r][c4+1] = v.y; As[r][c4+2] = v.z; As[r][c4+3] = v.w;
  }
#pragma unroll
  for (int i = 0; i < 8; ++i) {
    int id = t + i * 256;
    int r = id >> 4;
    int c4 = (id & 15) << 2;
    float4 v = *(const float4*)&Xb[(size_t)r * NL + l0 + c4];
    Xs[r][c4] = v.x; Xs[r][c4+1] = v.y; Xs[r][c4+2] = v.z; Xs[r][c4+3] = v.w;
  }
  __syncthreads();

  int tm = t >> 4, tl = t & 15;
  float acc[4][4] = {};
#pragma unroll 4
  for (int k = 0; k < 128; ++k) {
    float a0 = As[tm*4+0][k], a1 = As[tm*4+1][k], a2 = As[tm*4+2][k], a3 = As[tm*4+3][k];
    float4 xv = *(const float4*)&Xs[k][tl << 2];
    acc[0][0] += a0*xv.x; acc[0][1] += a0*xv.y; acc[0][2] += a0*xv.z; acc[0][3] += a0*xv.w;
    acc[1][0] += a1*xv.x; acc[1][1] += a1*xv.y; acc[1][2] += a1*xv.z; acc[1][3] += a1*xv.w;
    acc[2][0] += a2*xv.x; acc[2][1] += a2*xv.y; acc[2][2] += a2*xv.z; acc[2][3] += a2*xv.w;
    acc[3][0] += a3*xv.x; acc[3][1] += a3*xv.y; acc[3][2] += a3*xv.z; acc[3][3] += a3*xv.w;
  }

#pragma unroll
  for (int i = 0; i < 4; ++i) {
    int gr = m0 + tm * 4 + i;
    int sel = gr >> 7, w = gr & 127, h = w >> 4, kk = w & 15;
    size_t base = (size_t)sel * NTOT + (((size_t)h * NB + b) * NDK + kk) * NL;
#pragma unroll
    for (int j = 0; j < 4; ++j) out[base + l0 + tl * 4 + j] = acc[i][j];
  }
}

// ---------------- fused attention v3 ----------------
// softmax over query axis i, per key column j.
// grid: 768 blocks = (h*NB+b) * 4 j-quarters; 512 threads = 128 j x 4 i-quarters.
// Per thread: 128 i, processed in 4 online chunks of 32 with s held in registers
// (no recompute). Q,V staged in natural [k][i] layout; all LDS reads are
// wave-uniform broadcast ds_read_b128 (conflict-free by construction).
__device__ inline float4 fmax4(const float4 a, const float4 b) {
  return make_float4(fmaxf(a.x,b.x), fmaxf(a.y,b.y), fmaxf(a.z,b.z), fmaxf(a.w,b.w));
}

__global__ __launch_bounds__(512) void attn_kernel(const float* __restrict__ qkv,
                                                   float* __restrict__ headbuf) {
  __shared__ union {
    struct { float Q[16][512]; float V[16][512]; } s;                        // 64 KB
    struct { float pm[4][128]; float pl[4][128]; float pacc[4][128][20]; } c; // 44 KB
  } u;
  int bx = blockIdx.x;
  int hb = bx >> 2, jq = bx & 3;
  int h = hb / NB, b = hb % NB;
  const float* qp = qkv + (size_t)hb * NDK * NL;
  const float* kp = qp + NTOT;
  const float* vp = qp + 2 * NTOT;
  int t = threadIdx.x;

  // stage Q,V as straight contiguous float4 copies ([k][i] layout, no transpose)
  {
    const float4* qp4 = (const float4*)qp;
    const float4* vp4 = (const float4*)vp;
    float4* Q4 = (float4*)&u.s.Q[0][0];
    float4* V4 = (float4*)&u.s.V[0][0];
#pragma unroll
    for (int n = 0; n < 4; ++n) {
      int id = n * 512 + t;
      Q4[id] = qp4[id];
      V4[id] = vp4[id];
    }
  }
  __syncthreads();

  int j = t & 127, iq = t >> 7;
  int jg = jq * 128 + j;
  float kc[16];
#pragma unroll
  for (int v = 0; v < 16; ++v) kc[v] = kp[v * NL + jg] * 0.25f;  // fold 1/sqrt(dk)

  const int i0 = iq * 128;
  float M = -INFINITY, l = 0.0f;
  float acc[16] = {};

  for (int ch = 0; ch < 4; ++ch) {          // 4 chunks of 32 i
    int ib4 = (i0 + ch * 32) >> 2;          // float4 index base over i
    float4 s4[8];
#pragma unroll
    for (int g = 0; g < 8; ++g) {           // 4 i per group
      float4 sv = make_float4(0.f, 0.f, 0.f, 0.f);
#pragma unroll
      for (int k = 0; k < 16; ++k) {
        float4 qv = ((const float4*)&u.s.Q[k][0])[ib4 + g];   // broadcast b128
        sv.x = fmaf(qv.x, kc[k], sv.x);
        sv.y = fmaf(qv.y, kc[k], sv.y);
        sv.z = fmaf(qv.z, kc[k], sv.z);
        sv.w = fmaf(qv.w, kc[k], sv.w);
      }
      s4[g] = sv;
    }
    // chunk max (31 fmax)
    float4 m01 = fmax4(s4[0], s4[1]), m23 = fmax4(s4[2], s4[3]);
    float4 m45 = fmax4(s4[4], s4[5]), m67 = fmax4(s4[6], s4[7]);
    float4 mA = fmax4(fmax4(m01, m23), fmax4(m45, m67));
    float cm = fmaxf(fmaxf(mA.x, mA.y), fmaxf(mA.z, mA.w));
    float Mn = fmaxf(M, cm);
    float corr = __expf(M - Mn);            // first chunk: exp(-inf)=0
    M = Mn;
    l *= corr;
#pragma unroll
    for (int v = 0; v < 16; ++v) acc[v] *= corr;
    // exp + accumulate from registers (s4 stored; s - M <= 0 exactly)
#pragma unroll
    for (int g = 0; g < 8; ++g) {
      float4 p4;
      p4.x = __expf(s4[g].x - M);
      p4.y = __expf(s4[g].y - M);
      p4.z = __expf(s4[g].z - M);
      p4.w = __expf(s4[g].w - M);
      l += (p4.x + p4.y) + (p4.z + p4.w);
#pragma unroll
      for (int v = 0; v < 16; ++v) {
        float4 vv = ((const float4*)&u.s.V[v][0])[ib4 + g];   // broadcast b128
        acc[v] = fmaf(p4.x, vv.x, fmaf(p4.y, vv.y, fmaf(p4.z, vv.z, fmaf(p4.w, vv.w, acc[v]))));
      }
    }
  }

  __syncthreads();   // staging buffers dead; union reuse
  u.c.pm[iq][j] = M;
  u.c.pl[iq][j] = l;
  {
    float4* pr = (float4*)u.c.pacc[iq][j];
    pr[0] = make_float4(acc[0], acc[1], acc[2], acc[3]);
    pr[1] = make_float4(acc[4], acc[5], acc[6], acc[7]);
    pr[2] = make_float4(acc[8], acc[9], acc[10], acc[11]);
    pr[3] = make_float4(acc[12], acc[13], acc[14], acc[15]);
  }
  __syncthreads();

  // combine: thread (j, g=iq) merges 4 partials for v in [4g, 4g+4)
  int g = iq;
  float m0 = u.c.pm[0][j], m1 = u.c.pm[1][j], m2 = u.c.pm[2][j], m3 = u.c.pm[3][j];
  float Mt = fmaxf(fmaxf(m0, m1), fmaxf(m2, m3));
  float e0 = __expf(m0 - Mt), e1 = __expf(m1 - Mt), e2 = __expf(m2 - Mt), e3 = __expf(m3 - Mt);
  float L = u.c.pl[0][j]*e0 + u.c.pl[1][j]*e1 + u.c.pl[2][j]*e2 + u.c.pl[3][j]*e3;
  float invL = 1.0f / L;
  float4 h0 = ((const float4*)u.c.pacc[0][j])[g];
  float4 h1 = ((const float4*)u.c.pacc[1][j])[g];
  float4 h2 = ((const float4*)u.c.pacc[2][j])[g];
  float4 h3 = ((const float4*)u.c.pacc[3][j])[g];
  float* hp = headbuf + ((size_t)b * NC + h * NDK + g * 4) * NL + jg;
  hp[0*NL] = (h0.x*e0 + h1.x*e1 + h2.x*e2 + h3.x*e3) * invL;
  hp[1*NL] = (h0.y*e0 + h1.y*e1 + h2.y*e2 + h3.y*e3) * invL;
  hp[2*NL] = (h0.z*e0 + h1.z*e1 + h2.z*e2 + h3.z*e3) * invL;
  hp[3*NL] = (h0.w*e0 + h1.w*e1 + h2.w*e2 + h3.w*e3) * invL;
}

// ---------------- launch ----------------
extern "C" void kernel_launch(void* const* d_in, const int* in_sizes, int n_in,
                              void* d_out, int out_size, void* d_ws, size_t ws_size,
                              hipStream_t stream) {
  (void)in_sizes; (void)n_in; (void)out_size; (void)ws_size;
  const float* x    = (const float*)d_in[0];
  const float* dw_w = (const float*)d_in[1];
  const float* dw_b = (const float*)d_in[2];
  const float* pw_w = (const float*)d_in[3];
  const float* pw_b = (const float*)d_in[4];
  const float* Wq   = (const float*)d_in[5];
  const float* Wk   = (const float*)d_in[6];
  const float* Wv   = (const float*)d_in[7];
  const float* Wo   = (const float*)d_in[8];
  const float* W    = (const float*)d_in[9];
  float* out = (float*)d_out;

  const size_t N = NTOT;
  float* cur  = (float*)d_ws;
  float* bufA = cur + N;
  float* bufB = bufA + N;
  float* qkv  = bufB + N;     // 3*N

  uint32_t fk0[6], fk1[6];
  for (int i = 0; i < 6; ++i) {
    uint32_t a = 0u, bb = (uint32_t)i;
    tf2x32(0u, 7u, a, bb);
    fk0[i] = a; fk1[i] = bb;
  }

  pos_add_kernel<<<NTOT / 256, 256, 0, stream>>>(x, cur);

  for (int ci = 0; ci < 4; ++ci) {
    norm_dw_kernel<true><<<NB * NC, 64, 0, stream>>>(cur, bufB, dw_w + ci * NC * 7, dw_b + ci * NC);
    gemm128_kernel<0, false><<<dim3(8, 2, NB), 256, 0, stream>>>(
        pw_w + (size_t)ci * NC * NC, bufB, cur, pw_b + ci * NC, cur, fk0[ci], fk1[ci]);
  }

  norm_dw_kernel<false><<<NB * NC, 64, 0, stream>>>(cur, bufA, nullptr, nullptr);
  qkv_kernel<<<dim3(8, 6, NB), 256, 0, stream>>>(Wq, Wk, Wv, bufA, qkv);
  attn_kernel<<<NH * NB * 4, 512, 0, stream>>>(qkv, bufB);
  gemm128_kernel<1, true><<<dim3(8, 2, NB), 256, 0, stream>>>(
      Wo, bufB, cur, nullptr, cur, fk0[4], fk1[4]);

  norm_dw_kernel<false><<<NB * NC, 64, 0, stream>>>(cur, bufA, nullptr, nullptr);
  gemm128_kernel<2, true><<<dim3(8, 2, NB), 256, 0, stream>>>(
      W, bufA, out, nullptr, cur, fk0[5], fk1[5]);
}

// Round 9
// 211.641 us; speedup vs baseline: 1.3694x; 1.3694x over previous
//
#include <hip/hip_runtime.h>
#include <stdint.h>
#include <math.h>

#define NB 24
#define NC 128
#define NH 8
#define NDK 16
#define NL 512
#define NTOT (24*128*512)

typedef float f32x4 __attribute__((ext_vector_type(4)));
typedef short s16x4 __attribute__((ext_vector_type(4)));

__device__ inline f32x4 mfma_bf16_16x16x16(s16x4 a, s16x4 b, f32x4 c) {
#if defined(__HIP_DEVICE_COMPILE__)
#if __has_builtin(__builtin_amdgcn_mfma_f32_16x16x16bf16_1k)
  return __builtin_amdgcn_mfma_f32_16x16x16bf16_1k(a, b, c, 0, 0, 0);
#else
  return __builtin_amdgcn_mfma_f32_16x16x16_bf16(a, b, c, 0, 0, 0);
#endif
#else
  (void)a; (void)b;
  return c;  // host stub — never executed
#endif
}

__device__ inline unsigned short f2bf(float x) {   // RNE float->bf16
  uint32_t u = __float_as_uint(x);
  return (unsigned short)((u + 0x7FFFu + ((u >> 16) & 1u)) >> 16);
}
__device__ inline float bf2f(unsigned short s) {
  return __uint_as_float(((uint32_t)s) << 16);
}

// ---------------- threefry2x32 (JAX-compatible) ----------------
__host__ __device__ inline void tf2x32(uint32_t k0, uint32_t k1, uint32_t& x0, uint32_t& x1) {
  uint32_t ks2 = k0 ^ k1 ^ 0x1BD11BDAu;
  x0 += k0; x1 += k1;
#define TF_R(r) { x0 += x1; x1 = (x1 << r) | (x1 >> (32 - r)); x1 ^= x0; }
  TF_R(13) TF_R(15) TF_R(26) TF_R(6)
  x0 += k1;  x1 += ks2 + 1u;
  TF_R(17) TF_R(29) TF_R(16) TF_R(24)
  x0 += ks2; x1 += k0 + 2u;
  TF_R(13) TF_R(15) TF_R(26) TF_R(6)
  x0 += k0;  x1 += k1 + 3u;
  TF_R(17) TF_R(29) TF_R(16) TF_R(24)
  x0 += k1;  x1 += ks2 + 4u;
  TF_R(13) TF_R(15) TF_R(26) TF_R(6)
  x0 += ks2; x1 += k0 + 5u;
#undef TF_R
}

__device__ inline float drop_scale(uint32_t k0, uint32_t k1, uint32_t idx) {
  uint32_t x0 = 0u, x1 = idx;
  tf2x32(k0, k1, x0, x1);
  uint32_t bits = x0 ^ x1;
  float u = __uint_as_float((bits >> 9) | 0x3f800000u) - 1.0f;
  return (u < 0.9f) ? (1.0f / 0.9f) : 0.0f;
}

// ---------------- positional encoding + add ----------------
__global__ __launch_bounds__(256) void pos_add_kernel(const float* __restrict__ x,
                                                      float* __restrict__ out) {
  int idx = blockIdx.x * 256 + threadIdx.x;
  int l = idx & (NL - 1);
  int c = (idx >> 9) & (NC - 1);
  int ce = c & ~1;
  double base = exp(-(double)ce * 9.210340371976184 / 128.0); // ln(10000)
  float freq = (c & 1) ? -(float)base : (float)base;
  float phase = (c & 1) ? (float)(M_PI / 2.0) : 0.0f;
  float pe = sinf(sinf((float)l * freq + phase));
  out[idx] = x[idx] + pe;
}

// ---------------- fused layernorm (+ optional depthwise conv) ----------------
template<bool DO_CONV>
__global__ __launch_bounds__(64) void norm_dw_kernel(const float* __restrict__ in,
                                                     float* __restrict__ outp,
                                                     const float* __restrict__ dww,
                                                     const float* __restrict__ dwb) {
  int row = blockIdx.x;           // b*NC + c
  int c = row & (NC - 1);
  int t = threadIdx.x;
  const float* rp = in + (size_t)row * NL;
  float4 v0 = ((const float4*)rp)[t * 2];
  float4 v1 = ((const float4*)rp)[t * 2 + 1];
  float xr[8] = {v0.x, v0.y, v0.z, v0.w, v1.x, v1.y, v1.z, v1.w};
  float s = 0.f;
#pragma unroll
  for (int j = 0; j < 8; ++j) s += xr[j];
#pragma unroll
  for (int off = 32; off >= 1; off >>= 1) s += __shfl_xor(s, off);
  float mean = s * (1.0f / 512.0f);
  float sq = 0.f;
#pragma unroll
  for (int j = 0; j < 8; ++j) { xr[j] -= mean; sq += xr[j] * xr[j]; }
#pragma unroll
  for (int off = 32; off >= 1; off >>= 1) sq += __shfl_xor(sq, off);
  float inv = 1.0f / (sqrtf(sq * (1.0f / 511.0f)) + 1e-6f);

  if (!DO_CONV) {
    float4 o0 = make_float4(xr[0]*inv, xr[1]*inv, xr[2]*inv, xr[3]*inv);
    float4 o1 = make_float4(xr[4]*inv, xr[5]*inv, xr[6]*inv, xr[7]*inv);
    float4* op = (float4*)(outp + (size_t)row * NL);
    op[t * 2] = o0; op[t * 2 + 1] = o1;
  } else {
    __shared__ float rb[NL + 6];
    if (t < 3) { rb[t] = 0.f; rb[NL + 3 + t] = 0.f; }
#pragma unroll
    for (int j = 0; j < 8; ++j) rb[3 + t * 8 + j] = xr[j] * inv;
    __syncthreads();
    float w[7];
#pragma unroll
    for (int u = 0; u < 7; ++u) w[u] = dww[c * 7 + u];
    float bias = dwb[c];
    float* op = outp + (size_t)row * NL + t * 8;
#pragma unroll
    for (int j = 0; j < 8; ++j) {
      int l = t * 8 + j;
      float o = bias;
#pragma unroll
      for (int u = 0; u < 7; ++u) o += rb[l + u] * w[u];
      op[j] = o;
    }
  }
}

// ---------------- per-batch 128x128 @ 128x512 GEMM with fused epilogues ----------------
template<int EPI, bool A_PER_B>
__global__ __launch_bounds__(256) void gemm128_kernel(const float* __restrict__ A,
                                                      const float* __restrict__ X,
                                                      float* __restrict__ Y,
                                                      const float* __restrict__ bias,
                                                      const float* __restrict__ resid,
                                                      uint32_t k0, uint32_t k1) {
  __shared__ float As[64][129];
  __shared__ float Xs[128][68];
  int b  = blockIdx.z;
  int m0 = blockIdx.y * 64;
  int l0 = blockIdx.x * 64;
  int t  = threadIdx.x;
  const float* Ab = A + (A_PER_B ? (size_t)b * NC * NC : 0);
  const float* Xb = X + (size_t)b * NC * NL;

#pragma unroll
  for (int i = 0; i < 8; ++i) {
    int id = t + i * 256;
    int r = id >> 5;
    int c4 = (id & 31) << 2;
    float4 v = *(const float4*)&Ab[(size_t)(m0 + r) * NC + c4];
    As[r][c4] = v.x; As[r][c4+1] = v.y; As[r][c4+2] = v.z; As[r][c4+3] = v.w;
  }
#pragma unroll
  for (int i = 0; i < 8; ++i) {
    int id = t + i * 256;
    int r = id >> 4;
    int c4 = (id & 15) << 2;
    float4 v = *(const float4*)&Xb[(size_t)r * NL + l0 + c4];
    Xs[r][c4] = v.x; Xs[r][c4+1] = v.y; Xs[r][c4+2] = v.z; Xs[r][c4+3] = v.w;
  }
  __syncthreads();

  int tm = t >> 4, tl = t & 15;
  float acc[4][4] = {};
#pragma unroll 4
  for (int k = 0; k < 128; ++k) {
    float a0 = As[tm*4+0][k], a1 = As[tm*4+1][k], a2 = As[tm*4+2][k], a3 = As[tm*4+3][k];
    float4 xv = *(const float4*)&Xs[k][tl << 2];
    acc[0][0] += a0*xv.x; acc[0][1] += a0*xv.y; acc[0][2] += a0*xv.z; acc[0][3] += a0*xv.w;
    acc[1][0] += a1*xv.x; acc[1][1] += a1*xv.y; acc[1][2] += a1*xv.z; acc[1][3] += a1*xv.w;
    acc[2][0] += a2*xv.x; acc[2][1] += a2*xv.y; acc[2][2] += a2*xv.z; acc[2][3] += a2*xv.w;
    acc[3][0] += a3*xv.x; acc[3][1] += a3*xv.y; acc[3][2] += a3*xv.z; acc[3][3] += a3*xv.w;
  }

#pragma unroll
  for (int i = 0; i < 4; ++i) {
    int m = m0 + tm * 4 + i;
    float bv = (EPI == 0) ? bias[m] : 0.0f;
#pragma unroll
    for (int j = 0; j < 4; ++j) {
      int l = l0 + tl * 4 + j;
      float val = acc[i][j] + bv;
      if (EPI == 0 || EPI == 2) val = fmaxf(val, 0.0f);
      size_t idx = ((size_t)b * NC + m) * NL + l;
      float v2 = resid[idx] + val;
      float ds = drop_scale(k0, k1, (uint32_t)idx);
      Y[idx] = (ds == 0.0f) ? 0.0f : (v2 / 0.9f);
    }
  }
}

// ---------------- stacked QKV projection -> bf16 hi/lo outputs ----------------
// q is pre-scaled by 1/sqrt(dk)=0.25 and split hi/lo; k split hi/lo; v plain bf16.
__global__ __launch_bounds__(256) void qkv_kernel(const float* __restrict__ Wq,
                                                  const float* __restrict__ Wk,
                                                  const float* __restrict__ Wv,
                                                  const float* __restrict__ X,
                                                  unsigned short* __restrict__ qhw,
                                                  unsigned short* __restrict__ qlw,
                                                  unsigned short* __restrict__ khw,
                                                  unsigned short* __restrict__ klw,
                                                  unsigned short* __restrict__ vbw) {
  __shared__ float As[64][129];
  __shared__ float Xs[128][68];
  int b  = blockIdx.z;
  int m0 = blockIdx.y * 64;
  int l0 = blockIdx.x * 64;
  int t  = threadIdx.x;
  const float* Xb = X + (size_t)b * NC * NL;

#pragma unroll
  for (int i = 0; i < 8; ++i) {
    int id = t + i * 256;
    int r = id >> 5;
    int c4 = (id & 31) << 2;
    int gr = m0 + r;
    int sel = gr >> 7, w = gr & 127, h = w >> 4, kk = w & 15;
    const float* Wp = (sel == 0) ? Wq : ((sel == 1) ? Wk : Wv);
    const float* rowp = Wp + (((size_t)h * NB + b) * NDK + kk) * NC;
    float4 v = *(const float4*)&rowp[c4];
    As[r][c4] = v.x; As[r][c4+1] = v.y; As[r][c4+2] = v.z; As[r][c4+3] = v.w;
  }
#pragma unroll
  for (int i = 0; i < 8; ++i) {
    int id = t + i * 256;
    int r = id >> 4;
    int c4 = (id & 15) << 2;
    float4 v = *(const float4*)&Xb[(size_t)r * NL + l0 + c4];
    Xs[r][c4] = v.x; Xs[r][c4+1] = v.y; Xs[r][c4+2] = v.z; Xs[r][c4+3] = v.w;
  }
  __syncthreads();

  int tm = t >> 4, tl = t & 15;
  float acc[4][4] = {};
#pragma unroll 4
  for (int k = 0; k < 128; ++k) {
    float a0 = As[tm*4+0][k], a1 = As[tm*4+1][k], a2 = As[tm*4+2][k], a3 = As[tm*4+3][k];
    float4 xv = *(const float4*)&Xs[k][tl << 2];
    acc[0][0] += a0*xv.x; acc[0][1] += a0*xv.y; acc[0][2] += a0*xv.z; acc[0][3] += a0*xv.w;
    acc[1][0] += a1*xv.x; acc[1][1] += a1*xv.y; acc[1][2] += a1*xv.z; acc[1][3] += a1*xv.w;
    acc[2][0] += a2*xv.x; acc[2][1] += a2*xv.y; acc[2][2] += a2*xv.z; acc[2][3] += a2*xv.w;
    acc[3][0] += a3*xv.x; acc[3][1] += a3*xv.y; acc[3][2] += a3*xv.z; acc[3][3] += a3*xv.w;
  }

#pragma unroll
  for (int i = 0; i < 4; ++i) {
    int gr = m0 + tm * 4 + i;
    int sel = gr >> 7, w = gr & 127, h = w >> 4, kk = w & 15;
    size_t base = (((size_t)h * NB + b) * NDK + kk) * NL + l0 + tl * 4;
#pragma unroll
    for (int j = 0; j < 4; ++j) {
      float v = acc[i][j];
      size_t idx = base + j;
      if (sel == 0) {
        float s = v * 0.25f;
        unsigned short hi = f2bf(s);
        qhw[idx] = hi; qlw[idx] = f2bf(s - bf2f(hi));
      } else if (sel == 1) {
        unsigned short hi = f2bf(v);
        khw[idx] = hi; klw[idx] = f2bf(v - bf2f(hi));
      } else {
        vbw[idx] = f2bf(v);
      }
    }
  }
}

// ---------------- MFMA attention (softmax over query axis i) ----------------
// grid: dim3(4, H*B) -> block = (hb, j-quarter of 128). 256 thr = 4 waves,
// wave owns 2 j-tiles of 16. Loop i-tiles of 16: S-tile = 3x mfma_16x16x16
// (QhiKhi + QloKhi + QhiKlo, q pre-scaled); online softmax over rows (cross-group
// shfl max); P(bf16) feeds PV mfma directly (C layout == B layout, no shuffle).
__global__ __launch_bounds__(256) void attn_kernel(const unsigned short* __restrict__ qh,
                                                   const unsigned short* __restrict__ ql,
                                                   const unsigned short* __restrict__ kh,
                                                   const unsigned short* __restrict__ kl,
                                                   const unsigned short* __restrict__ vb,
                                                   float* __restrict__ headbuf) {
  __shared__ unsigned short KtH[128][16], KtL[128][16];                    // 8 KB
  __shared__ unsigned short QtH[2][16][16], QtL[2][16][16], Vt[2][16][16]; // 3 KB
  const int t = threadIdx.x;
  const int lane = t & 63, w = t >> 6;
  const int g = lane >> 4, j16 = lane & 15;
  const int hb = blockIdx.y, jq = blockIdx.x;
  const int j0 = jq * 128;
  const int h = hb / NB, b = hb % NB;
  const size_t kb = (size_t)hb * NDK * NL;

  { // stage K quarter: KtH/KtL[j][k]
    int j = t & 127, k8 = (t >> 7) * 8;
#pragma unroll
    for (int kk = 0; kk < 8; ++kk) {
      KtH[j][k8 + kk] = kh[kb + (size_t)(k8 + kk) * NL + j0 + j];
      KtL[j][k8 + kk] = kl[kb + (size_t)(k8 + kk) * NL + j0 + j];
    }
  }
  { // stage Q/V i-tile 0 (Q transposed [i][k]; V natural [v][i])
    int k_ = t >> 4, i_ = t & 15;
    size_t src = kb + (size_t)k_ * NL + i_;
    QtH[0][i_][k_] = qh[src];
    QtL[0][i_][k_] = ql[src];
    Vt [0][k_][i_] = vb[src];
  }
  __syncthreads();

  s16x4 KhiF[2], KloF[2];
#pragma unroll
  for (int q = 0; q < 2; ++q) {
    int jj = (w * 2 + q) * 16 + j16;
    KhiF[q] = *(const s16x4*)&KtH[jj][4 * g];
    KloF[q] = *(const s16x4*)&KtL[jj][4 * g];
  }

  float Mq[2] = {-INFINITY, -INFINITY};
  float lq[2] = {0.f, 0.f};
  f32x4 hC[2] = {{0.f, 0.f, 0.f, 0.f}, {0.f, 0.f, 0.f, 0.f}};

  int buf = 0;
  for (int it = 0; it < 32; ++it) {
    if (it < 31) {                       // prefetch next i-tile into other buffer
      int k_ = t >> 4, i_ = t & 15, nb = buf ^ 1;
      size_t src = kb + (size_t)k_ * NL + (it + 1) * 16 + i_;
      QtH[nb][i_][k_] = qh[src];
      QtL[nb][i_][k_] = ql[src];
      Vt [nb][k_][i_] = vb[src];
    }
    s16x4 Qhi = *(const s16x4*)&QtH[buf][j16][4 * g];
    s16x4 Qlo = *(const s16x4*)&QtL[buf][j16][4 * g];
    s16x4 Vf  = *(const s16x4*)&Vt [buf][j16][4 * g];
#pragma unroll
    for (int q = 0; q < 2; ++q) {
      f32x4 S = {0.f, 0.f, 0.f, 0.f};
      S = mfma_bf16_16x16x16(Qhi, KhiF[q], S);
      S = mfma_bf16_16x16x16(Qlo, KhiF[q], S);
      S = mfma_bf16_16x16x16(Qhi, KloF[q], S);
      float tm = fmaxf(fmaxf(S[0], S[1]), fmaxf(S[2], S[3]));
      tm = fmaxf(tm, __shfl_xor(tm, 16));
      tm = fmaxf(tm, __shfl_xor(tm, 32));
      float Mn = fmaxf(Mq[q], tm);
      float corr = __expf(Mq[q] - Mn);
      Mq[q] = Mn;
      float p0 = __expf(S[0] - Mn), p1 = __expf(S[1] - Mn);
      float p2 = __expf(S[2] - Mn), p3 = __expf(S[3] - Mn);
      lq[q] = lq[q] * corr + ((p0 + p1) + (p2 + p3));
      hC[q] = hC[q] * corr;
      union { uint32_t u[2]; s16x4 s; } bp;
      bp.u[0] = (uint32_t)f2bf(p0) | ((uint32_t)f2bf(p1) << 16);
      bp.u[1] = (uint32_t)f2bf(p2) | ((uint32_t)f2bf(p3) << 16);
      hC[q] = mfma_bf16_16x16x16(Vf, bp.s, hC[q]);
    }
    __syncthreads();
    buf ^= 1;
  }

#pragma unroll
  for (int q = 0; q < 2; ++q) {
    float l2 = lq[q] + __shfl_xor(lq[q], 16);
    float L  = l2 + __shfl_xor(l2, 32);
    float invL = 1.0f / L;
    int jglob = j0 + (w * 2 + q) * 16 + j16;
    float* hp = headbuf + ((size_t)b * NC + h * NDK + 4 * g) * NL + jglob;
    hp[0 * NL] = hC[q][0] * invL;
    hp[1 * NL] = hC[q][1] * invL;
    hp[2 * NL] = hC[q][2] * invL;
    hp[3 * NL] = hC[q][3] * invL;
  }
}

// ---------------- launch ----------------
extern "C" void kernel_launch(void* const* d_in, const int* in_sizes, int n_in,
                              void* d_out, int out_size, void* d_ws, size_t ws_size,
                              hipStream_t stream) {
  (void)in_sizes; (void)n_in; (void)out_size; (void)ws_size;
  const float* x    = (const float*)d_in[0];
  const float* dw_w = (const float*)d_in[1];
  const float* dw_b = (const float*)d_in[2];
  const float* pw_w = (const float*)d_in[3];
  const float* pw_b = (const float*)d_in[4];
  const float* Wq   = (const float*)d_in[5];
  const float* Wk   = (const float*)d_in[6];
  const float* Wv   = (const float*)d_in[7];
  const float* Wo   = (const float*)d_in[8];
  const float* W    = (const float*)d_in[9];
  float* out = (float*)d_out;

  const size_t N = NTOT;
  float* cur  = (float*)d_ws;
  float* bufA = cur + N;
  float* bufB = bufA + N;
  unsigned short* qh = (unsigned short*)(bufB + N);
  unsigned short* ql = qh + N;
  unsigned short* kh = ql + N;
  unsigned short* kl = kh + N;
  unsigned short* vb = kl + N;

  uint32_t fk0[6], fk1[6];
  for (int i = 0; i < 6; ++i) {
    uint32_t a = 0u, bb = (uint32_t)i;
    tf2x32(0u, 7u, a, bb);
    fk0[i] = a; fk1[i] = bb;
  }

  pos_add_kernel<<<NTOT / 256, 256, 0, stream>>>(x, cur);

  for (int ci = 0; ci < 4; ++ci) {
    norm_dw_kernel<true><<<NB * NC, 64, 0, stream>>>(cur, bufB, dw_w + ci * NC * 7, dw_b + ci * NC);
    gemm128_kernel<0, false><<<dim3(8, 2, NB), 256, 0, stream>>>(
        pw_w + (size_t)ci * NC * NC, bufB, cur, pw_b + ci * NC, cur, fk0[ci], fk1[ci]);
  }

  norm_dw_kernel<false><<<NB * NC, 64, 0, stream>>>(cur, bufA, nullptr, nullptr);
  qkv_kernel<<<dim3(8, 6, NB), 256, 0, stream>>>(Wq, Wk, Wv, bufA, qh, ql, kh, kl, vb);
  attn_kernel<<<dim3(4, NH * NB), 256, 0, stream>>>(qh, ql, kh, kl, vb, bufB);
  gemm128_kernel<1, true><<<dim3(8, 2, NB), 256, 0, stream>>>(
      Wo, bufB, cur, nullptr, cur, fk0[4], fk1[4]);

  norm_dw_kernel<false><<<NB * NC, 64, 0, stream>>>(cur, bufA, nullptr, nullptr);
  gemm128_kernel<2, true><<<dim3(8, 2, NB), 256, 0, stream>>>(
      W, bufA, out, nullptr, cur, fk0[5], fk1[5]);
}

// Round 10
// 208.313 us; speedup vs baseline: 1.3912x; 1.0160x over previous
//
#include <hip/hip_runtime.h>
#include <stdint.h>
#include <math.h>

#define NB 24
#define NC 128
#define NH 8
#define NDK 16
#define NL 512
#define NTOT (24*128*512)

typedef float f32x4 __attribute__((ext_vector_type(4)));
typedef short s16x4 __attribute__((ext_vector_type(4)));

__device__ inline f32x4 mfma_bf16_16x16x16(s16x4 a, s16x4 b, f32x4 c) {
#if defined(__HIP_DEVICE_COMPILE__)
#if __has_builtin(__builtin_amdgcn_mfma_f32_16x16x16bf16_1k)
  return __builtin_amdgcn_mfma_f32_16x16x16bf16_1k(a, b, c, 0, 0, 0);
#else
  return __builtin_amdgcn_mfma_f32_16x16x16_bf16(a, b, c, 0, 0, 0);
#endif
#else
  (void)a; (void)b;
  return c;  // host stub — never executed
#endif
}

__device__ inline unsigned short f2bf(float x) {   // RNE float->bf16
  uint32_t u = __float_as_uint(x);
  return (unsigned short)((u + 0x7FFFu + ((u >> 16) & 1u)) >> 16);
}
__device__ inline float bf2f(unsigned short s) {
  return __uint_as_float(((uint32_t)s) << 16);
}

// ---------------- threefry2x32 (JAX-compatible) ----------------
__host__ __device__ inline void tf2x32(uint32_t k0, uint32_t k1, uint32_t& x0, uint32_t& x1) {
  uint32_t ks2 = k0 ^ k1 ^ 0x1BD11BDAu;
  x0 += k0; x1 += k1;
#define TF_R(r) { x0 += x1; x1 = (x1 << r) | (x1 >> (32 - r)); x1 ^= x0; }
  TF_R(13) TF_R(15) TF_R(26) TF_R(6)
  x0 += k1;  x1 += ks2 + 1u;
  TF_R(17) TF_R(29) TF_R(16) TF_R(24)
  x0 += ks2; x1 += k0 + 2u;
  TF_R(13) TF_R(15) TF_R(26) TF_R(6)
  x0 += k0;  x1 += k1 + 3u;
  TF_R(17) TF_R(29) TF_R(16) TF_R(24)
  x0 += k1;  x1 += ks2 + 4u;
  TF_R(13) TF_R(15) TF_R(26) TF_R(6)
  x0 += ks2; x1 += k0 + 5u;
#undef TF_R
}

__device__ inline float drop_scale(uint32_t k0, uint32_t k1, uint32_t idx) {
  uint32_t x0 = 0u, x1 = idx;
  tf2x32(k0, k1, x0, x1);
  uint32_t bits = x0 ^ x1;
  float u = __uint_as_float((bits >> 9) | 0x3f800000u) - 1.0f;
  return (u < 0.9f) ? (1.0f / 0.9f) : 0.0f;
}

// ---------------- positional encoding + add ----------------
__global__ __launch_bounds__(256) void pos_add_kernel(const float* __restrict__ x,
                                                      float* __restrict__ out) {
  int idx = blockIdx.x * 256 + threadIdx.x;
  int l = idx & (NL - 1);
  int c = (idx >> 9) & (NC - 1);
  int ce = c & ~1;
  double base = exp(-(double)ce * 9.210340371976184 / 128.0); // ln(10000)
  float freq = (c & 1) ? -(float)base : (float)base;
  float phase = (c & 1) ? (float)(M_PI / 2.0) : 0.0f;
  float pe = sinf(sinf((float)l * freq + phase));
  out[idx] = x[idx] + pe;
}

// ---------------- fused layernorm (+ optional depthwise conv) ----------------
template<bool DO_CONV>
__global__ __launch_bounds__(64) void norm_dw_kernel(const float* __restrict__ in,
                                                     float* __restrict__ outp,
                                                     const float* __restrict__ dww,
                                                     const float* __restrict__ dwb) {
  int row = blockIdx.x;           // b*NC + c
  int c = row & (NC - 1);
  int t = threadIdx.x;
  const float* rp = in + (size_t)row * NL;
  float4 v0 = ((const float4*)rp)[t * 2];
  float4 v1 = ((const float4*)rp)[t * 2 + 1];
  float xr[8] = {v0.x, v0.y, v0.z, v0.w, v1.x, v1.y, v1.z, v1.w};
  float s = 0.f;
#pragma unroll
  for (int j = 0; j < 8; ++j) s += xr[j];
#pragma unroll
  for (int off = 32; off >= 1; off >>= 1) s += __shfl_xor(s, off);
  float mean = s * (1.0f / 512.0f);
  float sq = 0.f;
#pragma unroll
  for (int j = 0; j < 8; ++j) { xr[j] -= mean; sq += xr[j] * xr[j]; }
#pragma unroll
  for (int off = 32; off >= 1; off >>= 1) sq += __shfl_xor(sq, off);
  float inv = 1.0f / (sqrtf(sq * (1.0f / 511.0f)) + 1e-6f);

  if (!DO_CONV) {
    float4 o0 = make_float4(xr[0]*inv, xr[1]*inv, xr[2]*inv, xr[3]*inv);
    float4 o1 = make_float4(xr[4]*inv, xr[5]*inv, xr[6]*inv, xr[7]*inv);
    float4* op = (float4*)(outp + (size_t)row * NL);
    op[t * 2] = o0; op[t * 2 + 1] = o1;
  } else {
    __shared__ float rb[NL + 6];
    if (t < 3) { rb[t] = 0.f; rb[NL + 3 + t] = 0.f; }
#pragma unroll
    for (int j = 0; j < 8; ++j) rb[3 + t * 8 + j] = xr[j] * inv;
    __syncthreads();
    float w[7];
#pragma unroll
    for (int u = 0; u < 7; ++u) w[u] = dww[c * 7 + u];
    float bias = dwb[c];
    float* op = outp + (size_t)row * NL + t * 8;
#pragma unroll
    for (int j = 0; j < 8; ++j) {
      int l = t * 8 + j;
      float o = bias;
#pragma unroll
      for (int u = 0; u < 7; ++u) o += rb[l + u] * w[u];
      op[j] = o;
    }
  }
}

// ---------------- MFMA GEMM: per-batch (M=128) x (K=128) @ X(128 x 512) ----------------
// Split-bf16: A,X decomposed hi+lo; S = AhiXhi + AloXhi + AhiXlo (fp32 acc).
// Block: 256 thr = 4 waves; out region 64(M) x 64(N); wave w = M-tile w, 4 N-tiles.
// K chunked at 64; fragments: A row=lane&15 k=4g+e; X(B) col=lane&15; C row=4g+r col=lane&15.
// EPI: 0 = bias+relu+resid+dropout (pointwise conv), 1 = resid+dropout (Wo), 2 = relu+resid+dropout (W)
template<int EPI, bool A_PER_B>
__global__ __launch_bounds__(256) void gemm_mfma_kernel(const float* __restrict__ A,
                                                        const float* __restrict__ X,
                                                        float* __restrict__ Y,
                                                        const float* __restrict__ bias,
                                                        const float* __restrict__ resid,
                                                        uint32_t k0, uint32_t k1) {
  __shared__ unsigned short Ah[64][68], Al[64][68];   // [m][k]  (68: 8B-aligned rows)
  __shared__ unsigned short Xh[64][68], Xl[64][68];   // [n][k]  (transposed)
  int b  = blockIdx.z;
  int m0 = blockIdx.y * 64;
  int l0 = blockIdx.x * 64;
  int t  = threadIdx.x;
  const int lane = t & 63, w = t >> 6;
  const int g = lane >> 4, j16 = lane & 15;
  const float* Ab = A + (A_PER_B ? (size_t)b * NC * NC : 0);
  const float* Xb = X + (size_t)b * NC * NL;

  f32x4 acc[4] = {{0.f,0.f,0.f,0.f},{0.f,0.f,0.f,0.f},{0.f,0.f,0.f,0.f},{0.f,0.f,0.f,0.f}};

  for (int kc = 0; kc < 2; ++kc) {
    // stage A chunk (64 x 64 fp32 -> hi/lo)
#pragma unroll
    for (int i = 0; i < 4; ++i) {
      int id = t + i * 256;              // 1024 float4s
      int r = id >> 4, c4 = (id & 15) << 2;
      float4 v = *(const float4*)&Ab[(size_t)(m0 + r) * NC + kc * 64 + c4];
      unsigned short h0 = f2bf(v.x), h1 = f2bf(v.y), h2 = f2bf(v.z), h3 = f2bf(v.w);
      Ah[r][c4] = h0; Ah[r][c4+1] = h1; Ah[r][c4+2] = h2; Ah[r][c4+3] = h3;
      Al[r][c4]   = f2bf(v.x - bf2f(h0));
      Al[r][c4+1] = f2bf(v.y - bf2f(h1));
      Al[r][c4+2] = f2bf(v.z - bf2f(h2));
      Al[r][c4+3] = f2bf(v.w - bf2f(h3));
    }
    // stage X chunk transposed ([k][L] -> [n][k]), hi/lo
    {
      int n = t & 63, kbase = (t >> 6) * 16;
#pragma unroll
      for (int kk = 0; kk < 16; ++kk) {
        float v = Xb[(size_t)(kc * 64 + kbase + kk) * NL + l0 + n];
        unsigned short hi = f2bf(v);
        Xh[n][kbase + kk] = hi;
        Xl[n][kbase + kk] = f2bf(v - bf2f(hi));
      }
    }
    __syncthreads();
#pragma unroll
    for (int ks = 0; ks < 4; ++ks) {
      int ko = ks * 16 + 4 * g;
      s16x4 a_h = *(const s16x4*)&Ah[w * 16 + j16][ko];
      s16x4 a_l = *(const s16x4*)&Al[w * 16 + j16][ko];
#pragma unroll
      for (int nt = 0; nt < 4; ++nt) {
        s16x4 x_h = *(const s16x4*)&Xh[nt * 16 + j16][ko];
        s16x4 x_l = *(const s16x4*)&Xl[nt * 16 + j16][ko];
        acc[nt] = mfma_bf16_16x16x16(a_h, x_h, acc[nt]);
        acc[nt] = mfma_bf16_16x16x16(a_l, x_h, acc[nt]);
        acc[nt] = mfma_bf16_16x16x16(a_h, x_l, acc[nt]);
      }
    }
    __syncthreads();
  }

#pragma unroll
  for (int nt = 0; nt < 4; ++nt) {
    int n = l0 + nt * 16 + j16;
#pragma unroll
    for (int r = 0; r < 4; ++r) {
      int m = m0 + w * 16 + 4 * g + r;
      float val = acc[nt][r] + ((EPI == 0) ? bias[m] : 0.0f);
      if (EPI == 0 || EPI == 2) val = fmaxf(val, 0.0f);
      size_t idx = ((size_t)b * NC + m) * NL + n;
      float v2 = resid[idx] + val;
      float ds = drop_scale(k0, k1, (uint32_t)idx);
      Y[idx] = (ds == 0.0f) ? 0.0f : (v2 / 0.9f);
    }
  }
}

// ---------------- MFMA QKV projection: (384 x 128) @ (128 x 512) per b ----------------
// Same structure; epilogue emits q (pre-scaled 0.25, hi/lo), k (hi/lo), v (bf16).
__global__ __launch_bounds__(256) void qkv_mfma_kernel(const float* __restrict__ Wq,
                                                       const float* __restrict__ Wk,
                                                       const float* __restrict__ Wv,
                                                       const float* __restrict__ X,
                                                       unsigned short* __restrict__ qhw,
                                                       unsigned short* __restrict__ qlw,
                                                       unsigned short* __restrict__ khw,
                                                       unsigned short* __restrict__ klw,
                                                       unsigned short* __restrict__ vbw) {
  __shared__ unsigned short Ah[64][68], Al[64][68];
  __shared__ unsigned short Xh[64][68], Xl[64][68];
  int b  = blockIdx.z;
  int m0 = blockIdx.y * 64;          // 0..5 * 64; sel = m0>>7 uniform per block
  int l0 = blockIdx.x * 64;
  int t  = threadIdx.x;
  const int lane = t & 63, w = t >> 6;
  const int g = lane >> 4, j16 = lane & 15;
  const int sel = m0 >> 7;
  const float* Wp = (sel == 0) ? Wq : ((sel == 1) ? Wk : Wv);
  const float* Xb = X + (size_t)b * NC * NL;

  f32x4 acc[4] = {{0.f,0.f,0.f,0.f},{0.f,0.f,0.f,0.f},{0.f,0.f,0.f,0.f},{0.f,0.f,0.f,0.f}};

  for (int kc = 0; kc < 2; ++kc) {
#pragma unroll
    for (int i = 0; i < 4; ++i) {
      int id = t + i * 256;
      int r = id >> 4, c4 = (id & 15) << 2;
      int gr = m0 + r;
      int w_ = gr & 127, h = w_ >> 4, kk = w_ & 15;
      const float* rowp = Wp + (((size_t)h * NB + b) * NDK + kk) * NC + kc * 64;
      float4 v = *(const float4*)&rowp[c4];
      unsigned short h0 = f2bf(v.x), h1 = f2bf(v.y), h2 = f2bf(v.z), h3 = f2bf(v.w);
      Ah[r][c4] = h0; Ah[r][c4+1] = h1; Ah[r][c4+2] = h2; Ah[r][c4+3] = h3;
      Al[r][c4]   = f2bf(v.x - bf2f(h0));
      Al[r][c4+1] = f2bf(v.y - bf2f(h1));
      Al[r][c4+2] = f2bf(v.z - bf2f(h2));
      Al[r][c4+3] = f2bf(v.w - bf2f(h3));
    }
    {
      int n = t & 63, kbase = (t >> 6) * 16;
#pragma unroll
      for (int kk = 0; kk < 16; ++kk) {
        float v = Xb[(size_t)(kc * 64 + kbase + kk) * NL + l0 + n];
        unsigned short hi = f2bf(v);
        Xh[n][kbase + kk] = hi;
        Xl[n][kbase + kk] = f2bf(v - bf2f(hi));
      }
    }
    __syncthreads();
#pragma unroll
    for (int ks = 0; ks < 4; ++ks) {
      int ko = ks * 16 + 4 * g;
      s16x4 a_h = *(const s16x4*)&Ah[w * 16 + j16][ko];
      s16x4 a_l = *(const s16x4*)&Al[w * 16 + j16][ko];
#pragma unroll
      for (int nt = 0; nt < 4; ++nt) {
        s16x4 x_h = *(const s16x4*)&Xh[nt * 16 + j16][ko];
        s16x4 x_l = *(const s16x4*)&Xl[nt * 16 + j16][ko];
        acc[nt] = mfma_bf16_16x16x16(a_h, x_h, acc[nt]);
        acc[nt] = mfma_bf16_16x16x16(a_l, x_h, acc[nt]);
        acc[nt] = mfma_bf16_16x16x16(a_h, x_l, acc[nt]);
      }
    }
    __syncthreads();
  }

#pragma unroll
  for (int nt = 0; nt < 4; ++nt) {
    int n = l0 + nt * 16 + j16;
#pragma unroll
    for (int r = 0; r < 4; ++r) {
      int grow = m0 + w * 16 + 4 * g + r;
      int w_ = grow & 127, h = w_ >> 4, kk = w_ & 15;
      size_t idx = (((size_t)h * NB + b) * NDK + kk) * NL + n;
      float v = acc[nt][r];
      if (sel == 0) {
        float s = v * 0.25f;
        unsigned short hi = f2bf(s);
        qhw[idx] = hi; qlw[idx] = f2bf(s - bf2f(hi));
      } else if (sel == 1) {
        unsigned short hi = f2bf(v);
        khw[idx] = hi; klw[idx] = f2bf(v - bf2f(hi));
      } else {
        vbw[idx] = f2bf(v);
      }
    }
  }
}

// ---------------- MFMA attention (softmax over query axis i) ----------------
__global__ __launch_bounds__(256) void attn_kernel(const unsigned short* __restrict__ qh,
                                                   const unsigned short* __restrict__ ql,
                                                   const unsigned short* __restrict__ kh,
                                                   const unsigned short* __restrict__ kl,
                                                   const unsigned short* __restrict__ vb,
                                                   float* __restrict__ headbuf) {
  __shared__ unsigned short KtH[128][16], KtL[128][16];                    // 8 KB
  __shared__ unsigned short QtH[2][16][16], QtL[2][16][16], Vt[2][16][16]; // 3 KB
  const int t = threadIdx.x;
  const int lane = t & 63, w = t >> 6;
  const int g = lane >> 4, j16 = lane & 15;
  const int hb = blockIdx.y, jq = blockIdx.x;
  const int j0 = jq * 128;
  const int h = hb / NB, b = hb % NB;
  const size_t kb = (size_t)hb * NDK * NL;

  { // stage K quarter: KtH/KtL[j][k]
    int j = t & 127, k8 = (t >> 7) * 8;
#pragma unroll
    for (int kk = 0; kk < 8; ++kk) {
      KtH[j][k8 + kk] = kh[kb + (size_t)(k8 + kk) * NL + j0 + j];
      KtL[j][k8 + kk] = kl[kb + (size_t)(k8 + kk) * NL + j0 + j];
    }
  }
  { // stage Q/V i-tile 0 (Q transposed [i][k]; V natural [v][i])
    int k_ = t >> 4, i_ = t & 15;
    size_t src = kb + (size_t)k_ * NL + i_;
    QtH[0][i_][k_] = qh[src];
    QtL[0][i_][k_] = ql[src];
    Vt [0][k_][i_] = vb[src];
  }
  __syncthreads();

  s16x4 KhiF[2], KloF[2];
#pragma unroll
  for (int q = 0; q < 2; ++q) {
    int jj = (w * 2 + q) * 16 + j16;
    KhiF[q] = *(const s16x4*)&KtH[jj][4 * g];
    KloF[q] = *(const s16x4*)&KtL[jj][4 * g];
  }

  float Mq[2] = {-INFINITY, -INFINITY};
  float lq[2] = {0.f, 0.f};
  f32x4 hC[2] = {{0.f, 0.f, 0.f, 0.f}, {0.f, 0.f, 0.f, 0.f}};

  int buf = 0;
  for (int it = 0; it < 32; ++it) {
    if (it < 31) {                       // prefetch next i-tile into other buffer
      int k_ = t >> 4, i_ = t & 15, nb = buf ^ 1;
      size_t src = kb + (size_t)k_ * NL + (it + 1) * 16 + i_;
      QtH[nb][i_][k_] = qh[src];
      QtL[nb][i_][k_] = ql[src];
      Vt [nb][k_][i_] = vb[src];
    }
    s16x4 Qhi = *(const s16x4*)&QtH[buf][j16][4 * g];
    s16x4 Qlo = *(const s16x4*)&QtL[buf][j16][4 * g];
    s16x4 Vf  = *(const s16x4*)&Vt [buf][j16][4 * g];
#pragma unroll
    for (int q = 0; q < 2; ++q) {
      f32x4 S = {0.f, 0.f, 0.f, 0.f};
      S = mfma_bf16_16x16x16(Qhi, KhiF[q], S);
      S = mfma_bf16_16x16x16(Qlo, KhiF[q], S);
      S = mfma_bf16_16x16x16(Qhi, KloF[q], S);
      float tm = fmaxf(fmaxf(S[0], S[1]), fmaxf(S[2], S[3]));
      tm = fmaxf(tm, __shfl_xor(tm, 16));
      tm = fmaxf(tm, __shfl_xor(tm, 32));
      float Mn = fmaxf(Mq[q], tm);
      float corr = __expf(Mq[q] - Mn);
      Mq[q] = Mn;
      float p0 = __expf(S[0] - Mn), p1 = __expf(S[1] - Mn);
      float p2 = __expf(S[2] - Mn), p3 = __expf(S[3] - Mn);
      lq[q] = lq[q] * corr + ((p0 + p1) + (p2 + p3));
      hC[q] = hC[q] * corr;
      union { uint32_t u[2]; s16x4 s; } bp;
      bp.u[0] = (uint32_t)f2bf(p0) | ((uint32_t)f2bf(p1) << 16);
      bp.u[1] = (uint32_t)f2bf(p2) | ((uint32_t)f2bf(p3) << 16);
      hC[q] = mfma_bf16_16x16x16(Vf, bp.s, hC[q]);
    }
    __syncthreads();
    buf ^= 1;
  }

#pragma unroll
  for (int q = 0; q < 2; ++q) {
    float l2 = lq[q] + __shfl_xor(lq[q], 16);
    float L  = l2 + __shfl_xor(l2, 32);
    float invL = 1.0f / L;
    int jglob = j0 + (w * 2 + q) * 16 + j16;
    float* hp = headbuf + ((size_t)b * NC + h * NDK + 4 * g) * NL + jglob;
    hp[0 * NL] = hC[q][0] * invL;
    hp[1 * NL] = hC[q][1] * invL;
    hp[2 * NL] = hC[q][2] * invL;
    hp[3 * NL] = hC[q][3] * invL;
  }
}

// ---------------- launch ----------------
extern "C" void kernel_launch(void* const* d_in, const int* in_sizes, int n_in,
                              void* d_out, int out_size, void* d_ws, size_t ws_size,
                              hipStream_t stream) {
  (void)in_sizes; (void)n_in; (void)out_size; (void)ws_size;
  const float* x    = (const float*)d_in[0];
  const float* dw_w = (const float*)d_in[1];
  const float* dw_b = (const float*)d_in[2];
  const float* pw_w = (const float*)d_in[3];
  const float* pw_b = (const float*)d_in[4];
  const float* Wq   = (const float*)d_in[5];
  const float* Wk   = (const float*)d_in[6];
  const float* Wv   = (const float*)d_in[7];
  const float* Wo   = (const float*)d_in[8];
  const float* W    = (const float*)d_in[9];
  float* out = (float*)d_out;

  const size_t N = NTOT;
  float* cur  = (float*)d_ws;
  float* bufA = cur + N;
  float* bufB = bufA + N;
  unsigned short* qh = (unsigned short*)(bufB + N);
  unsigned short* ql = qh + N;
  unsigned short* kh = ql + N;
  unsigned short* kl = kh + N;
  unsigned short* vb = kl + N;

  uint32_t fk0[6], fk1[6];
  for (int i = 0; i < 6; ++i) {
    uint32_t a = 0u, bb = (uint32_t)i;
    tf2x32(0u, 7u, a, bb);
    fk0[i] = a; fk1[i] = bb;
  }

  pos_add_kernel<<<NTOT / 256, 256, 0, stream>>>(x, cur);

  for (int ci = 0; ci < 4; ++ci) {
    norm_dw_kernel<true><<<NB * NC, 64, 0, stream>>>(cur, bufB, dw_w + ci * NC * 7, dw_b + ci * NC);
    gemm_mfma_kernel<0, false><<<dim3(8, 2, NB), 256, 0, stream>>>(
        pw_w + (size_t)ci * NC * NC, bufB, cur, pw_b + ci * NC, cur, fk0[ci], fk1[ci]);
  }

  norm_dw_kernel<false><<<NB * NC, 64, 0, stream>>>(cur, bufA, nullptr, nullptr);
  qkv_mfma_kernel<<<dim3(8, 6, NB), 256, 0, stream>>>(Wq, Wk, Wv, bufA, qh, ql, kh, kl, vb);
  attn_kernel<<<dim3(4, NH * NB), 256, 0, stream>>>(qh, ql, kh, kl, vb, bufB);
  gemm_mfma_kernel<1, true><<<dim3(8, 2, NB), 256, 0, stream>>>(
      Wo, bufB, cur, nullptr, cur, fk0[4], fk1[4]);

  norm_dw_kernel<false><<<NB * NC, 64, 0, stream>>>(cur, bufA, nullptr, nullptr);
  gemm_mfma_kernel<2, true><<<dim3(8, 2, NB), 256, 0, stream>>>(
      W, bufA, out, nullptr, cur, fk0[5], fk1[5]);
}

// Round 11
// 186.632 us; speedup vs baseline: 1.5529x; 1.1162x over previous
//
#include <hip/hip_runtime.h>
#include <stdint.h>
#include <math.h>

#define NB 24
#define NC 128
#define NH 8
#define NDK 16
#define NL 512
#define NTOT (24*128*512)

typedef float f32x4 __attribute__((ext_vector_type(4)));
typedef short s16x4 __attribute__((ext_vector_type(4)));

__device__ inline f32x4 mfma_bf16_16x16x16(s16x4 a, s16x4 b, f32x4 c) {
#if defined(__HIP_DEVICE_COMPILE__)
#if __has_builtin(__builtin_amdgcn_mfma_f32_16x16x16bf16_1k)
  return __builtin_amdgcn_mfma_f32_16x16x16bf16_1k(a, b, c, 0, 0, 0);
#else
  return __builtin_amdgcn_mfma_f32_16x16x16_bf16(a, b, c, 0, 0, 0);
#endif
#else
  (void)a; (void)b;
  return c;  // host stub — never executed
#endif
}

__device__ inline unsigned short f2bf(float x) {   // RNE float->bf16
  uint32_t u = __float_as_uint(x);
  return (unsigned short)((u + 0x7FFFu + ((u >> 16) & 1u)) >> 16);
}
__device__ inline float bf2f(unsigned short s) {
  return __uint_as_float(((uint32_t)s) << 16);
}

// ---------------- threefry2x32 (JAX-compatible) ----------------
__host__ __device__ inline void tf2x32(uint32_t k0, uint32_t k1, uint32_t& x0, uint32_t& x1) {
  uint32_t ks2 = k0 ^ k1 ^ 0x1BD11BDAu;
  x0 += k0; x1 += k1;
#define TF_R(r) { x0 += x1; x1 = (x1 << r) | (x1 >> (32 - r)); x1 ^= x0; }
  TF_R(13) TF_R(15) TF_R(26) TF_R(6)
  x0 += k1;  x1 += ks2 + 1u;
  TF_R(17) TF_R(29) TF_R(16) TF_R(24)
  x0 += ks2; x1 += k0 + 2u;
  TF_R(13) TF_R(15) TF_R(26) TF_R(6)
  x0 += k0;  x1 += k1 + 3u;
  TF_R(17) TF_R(29) TF_R(16) TF_R(24)
  x0 += k1;  x1 += ks2 + 4u;
  TF_R(13) TF_R(15) TF_R(26) TF_R(6)
  x0 += ks2; x1 += k0 + 5u;
#undef TF_R
}

__device__ inline float drop_scale(uint32_t k0, uint32_t k1, uint32_t idx) {
  uint32_t x0 = 0u, x1 = idx;
  tf2x32(k0, k1, x0, x1);
  uint32_t bits = x0 ^ x1;
  float u = __uint_as_float((bits >> 9) | 0x3f800000u) - 1.0f;
  return (u < 0.9f) ? (1.0f / 0.9f) : 0.0f;
}

// ---------------- weight split prep: fp32 -> bf16 hi/lo, once ----------------
#define S0 (4*128*128)
#define SW (24*128*128)
#define SQ (8*24*16*128)
// arena ushort offsets
#define oPwH 0
#define oPwL (S0)
#define oWoH (2*S0)
#define oWoL (2*S0 + SW)
#define oWH  (2*S0 + 2*SW)
#define oWL  (2*S0 + 3*SW)
#define oQH  (2*S0 + 4*SW)
#define oQL  (2*S0 + 4*SW + SQ)
#define oKH  (2*S0 + 4*SW + 2*SQ)
#define oKL  (2*S0 + 4*SW + 3*SQ)
#define oVH  (2*S0 + 4*SW + 4*SQ)
#define oVL  (2*S0 + 4*SW + 5*SQ)
#define PREP_TOT (S0 + 2*SW + 3*SQ)   // 2031616 = 7936 * 256

__global__ __launch_bounds__(256) void prep_split_kernel(
    const float* __restrict__ pw_w, const float* __restrict__ Wo, const float* __restrict__ W,
    const float* __restrict__ Wq, const float* __restrict__ Wk, const float* __restrict__ Wv,
    unsigned short* __restrict__ ws) {
  int idx = blockIdx.x * 256 + threadIdx.x;
  const float* src; unsigned short *dh, *dl; int off;
  if (idx < S0)                { src = pw_w; dh = ws + oPwH; dl = ws + oPwL; off = idx; }
  else if (idx < S0 + SW)      { src = Wo;   dh = ws + oWoH; dl = ws + oWoL; off = idx - S0; }
  else if (idx < S0 + 2*SW)    { src = W;    dh = ws + oWH;  dl = ws + oWL;  off = idx - S0 - SW; }
  else if (idx < S0 + 2*SW + SQ)   { src = Wq; dh = ws + oQH; dl = ws + oQL; off = idx - S0 - 2*SW; }
  else if (idx < S0 + 2*SW + 2*SQ) { src = Wk; dh = ws + oKH; dl = ws + oKL; off = idx - S0 - 2*SW - SQ; }
  else                             { src = Wv; dh = ws + oVH; dl = ws + oVL; off = idx - S0 - 2*SW - 2*SQ; }
  float v = src[off];
  unsigned short hi = f2bf(v);
  dh[off] = hi;
  dl[off] = f2bf(v - bf2f(hi));
}

// ---------------- fused [pos-enc +] layernorm [+ depthwise conv] -> bf16 hi/lo ----------------
// one wave per (b,c) row. ADD_PE: reads x, writes cur = x + pe (fp32) and norms that.
template<bool DO_CONV, bool ADD_PE>
__global__ __launch_bounds__(64) void norm_dw_kernel(const float* __restrict__ in,
                                                     float* __restrict__ cur_out,
                                                     unsigned short* __restrict__ oh,
                                                     unsigned short* __restrict__ ol,
                                                     const float* __restrict__ dww,
                                                     const float* __restrict__ dwb) {
  int row = blockIdx.x;           // b*NC + c
  int c = row & (NC - 1);
  int t = threadIdx.x;
  const float* rp = in + (size_t)row * NL;
  float4 v0 = ((const float4*)rp)[t * 2];
  float4 v1 = ((const float4*)rp)[t * 2 + 1];
  float xr[8] = {v0.x, v0.y, v0.z, v0.w, v1.x, v1.y, v1.z, v1.w};
  if (ADD_PE) {
    int ce = c & ~1;
    double base = exp(-(double)ce * 9.210340371976184 / 128.0); // ln(10000)
    float freq = (c & 1) ? -(float)base : (float)base;
    float phase = (c & 1) ? (float)(M_PI / 2.0) : 0.0f;
#pragma unroll
    for (int j = 0; j < 8; ++j)
      xr[j] += sinf(sinf((float)(t * 8 + j) * freq + phase));
    float4 o0 = make_float4(xr[0], xr[1], xr[2], xr[3]);
    float4 o1 = make_float4(xr[4], xr[5], xr[6], xr[7]);
    float4* cp = (float4*)(cur_out + (size_t)row * NL);
    cp[t * 2] = o0; cp[t * 2 + 1] = o1;
  }
  float s = 0.f;
#pragma unroll
  for (int j = 0; j < 8; ++j) s += xr[j];
#pragma unroll
  for (int off = 32; off >= 1; off >>= 1) s += __shfl_xor(s, off);
  float mean = s * (1.0f / 512.0f);
  float sq = 0.f;
#pragma unroll
  for (int j = 0; j < 8; ++j) { xr[j] -= mean; sq += xr[j] * xr[j]; }
#pragma unroll
  for (int off = 32; off >= 1; off >>= 1) sq += __shfl_xor(sq, off);
  float inv = 1.0f / (sqrtf(sq * (1.0f / 511.0f)) + 1e-6f);

  size_t obase = (size_t)row * NL + t * 8;
  if (!DO_CONV) {
#pragma unroll
    for (int j = 0; j < 8; ++j) {
      float o = xr[j] * inv;
      unsigned short hi = f2bf(o);
      oh[obase + j] = hi;
      ol[obase + j] = f2bf(o - bf2f(hi));
    }
  } else {
    __shared__ float rb[NL + 6];
    if (t < 3) { rb[t] = 0.f; rb[NL + 3 + t] = 0.f; }
#pragma unroll
    for (int j = 0; j < 8; ++j) rb[3 + t * 8 + j] = xr[j] * inv;
    __syncthreads();
    float w[7];
#pragma unroll
    for (int u = 0; u < 7; ++u) w[u] = dww[c * 7 + u];
    float bias = dwb[c];
#pragma unroll
    for (int j = 0; j < 8; ++j) {
      int l = t * 8 + j;
      float o = bias;
#pragma unroll
      for (int u = 0; u < 7; ++u) o += rb[l + u] * w[u];
      unsigned short hi = f2bf(o);
      oh[obase + j] = hi;
      ol[obase + j] = f2bf(o - bf2f(hi));
    }
  }
}

// ---------------- MFMA GEMM with pre-split operands ----------------
// A (hi/lo ushort) [M][K]; X (hi/lo ushort) [b][K][L]. 64x64 out per block, 4 waves.
// EPI: 0 = bias+relu+resid+dropout, 1 = resid+dropout, 2 = relu+resid+dropout
template<int EPI, bool A_PER_B>
__global__ __launch_bounds__(256) void gemm_mfma_kernel(
    const unsigned short* __restrict__ AhB, const unsigned short* __restrict__ AlB,
    const unsigned short* __restrict__ XhB, const unsigned short* __restrict__ XlB,
    float* __restrict__ Y, const float* __restrict__ bias, const float* __restrict__ resid,
    uint32_t k0, uint32_t k1) {
  __shared__ unsigned short Ah[64][68], Al[64][68];   // [m][k]
  __shared__ unsigned short Xh[64][68], Xl[64][68];   // [n][k]
  int b  = blockIdx.z;
  int m0 = blockIdx.y * 64;
  int l0 = blockIdx.x * 64;
  int t  = threadIdx.x;
  const int lane = t & 63, w = t >> 6;
  const int g = lane >> 4, j16 = lane & 15;
  const unsigned short* Abh = AhB + (A_PER_B ? (size_t)b * NC * NC : 0);
  const unsigned short* Abl = AlB + (A_PER_B ? (size_t)b * NC * NC : 0);
  const size_t xb = (size_t)b * NC * NL;

  f32x4 acc[4] = {{0.f,0.f,0.f,0.f},{0.f,0.f,0.f,0.f},{0.f,0.f,0.f,0.f},{0.f,0.f,0.f,0.f}};

  for (int kc = 0; kc < 2; ++kc) {
#pragma unroll
    for (int i = 0; i < 4; ++i) {           // A tile: 2 x 4096 ushorts as ushort4 units
      int id = t + i * 256;
      int r = id >> 4, u = (id & 15) << 2;
      *(s16x4*)&Ah[r][u] = *(const s16x4*)&Abh[(size_t)(m0 + r) * NC + kc * 64 + u];
      *(s16x4*)&Al[r][u] = *(const s16x4*)&Abl[(size_t)(m0 + r) * NC + kc * 64 + u];
    }
    {
      int n = t & 63, kq = (t >> 6) * 16;
#pragma unroll
      for (int kk = 0; kk < 16; ++kk) {
        int k = kq + kk;
        size_t src = xb + (size_t)(kc * 64 + k) * NL + l0 + n;
        Xh[n][k] = XhB[src];
        Xl[n][k] = XlB[src];
      }
    }
    __syncthreads();
#pragma unroll
    for (int ks = 0; ks < 4; ++ks) {
      int ko = ks * 16 + 4 * g;
      s16x4 a_h = *(const s16x4*)&Ah[w * 16 + j16][ko];
      s16x4 a_l = *(const s16x4*)&Al[w * 16 + j16][ko];
#pragma unroll
      for (int nt = 0; nt < 4; ++nt) {
        s16x4 x_h = *(const s16x4*)&Xh[nt * 16 + j16][ko];
        s16x4 x_l = *(const s16x4*)&Xl[nt * 16 + j16][ko];
        acc[nt] = mfma_bf16_16x16x16(a_h, x_h, acc[nt]);
        acc[nt] = mfma_bf16_16x16x16(a_l, x_h, acc[nt]);
        acc[nt] = mfma_bf16_16x16x16(a_h, x_l, acc[nt]);
      }
    }
    __syncthreads();
  }

#pragma unroll
  for (int nt = 0; nt < 4; ++nt) {
    int n = l0 + nt * 16 + j16;
#pragma unroll
    for (int r = 0; r < 4; ++r) {
      int m = m0 + w * 16 + 4 * g + r;
      float val = acc[nt][r] + ((EPI == 0) ? bias[m] : 0.0f);
      if (EPI == 0 || EPI == 2) val = fmaxf(val, 0.0f);
      size_t idx = ((size_t)b * NC + m) * NL + n;
      float v2 = resid[idx] + val;
      float ds = drop_scale(k0, k1, (uint32_t)idx);
      Y[idx] = (ds == 0.0f) ? 0.0f : (v2 / 0.9f);
    }
  }
}

// ---------------- MFMA QKV projection with pre-split operands ----------------
__global__ __launch_bounds__(256) void qkv_mfma_kernel(
    const unsigned short* __restrict__ wsp,
    const unsigned short* __restrict__ XhB, const unsigned short* __restrict__ XlB,
    unsigned short* __restrict__ qhw, unsigned short* __restrict__ qlw,
    unsigned short* __restrict__ khw, unsigned short* __restrict__ klw,
    unsigned short* __restrict__ vbw) {
  __shared__ unsigned short Ah[64][68], Al[64][68];
  __shared__ unsigned short Xh[64][68], Xl[64][68];
  int b  = blockIdx.z;
  int m0 = blockIdx.y * 64;          // sel = m0>>7 uniform per block
  int l0 = blockIdx.x * 64;
  int t  = threadIdx.x;
  const int lane = t & 63, w = t >> 6;
  const int g = lane >> 4, j16 = lane & 15;
  const int sel = m0 >> 7;
  const unsigned short* WpH = wsp + ((sel == 0) ? oQH : (sel == 1) ? oKH : oVH);
  const unsigned short* WpL = wsp + ((sel == 0) ? oQL : (sel == 1) ? oKL : oVL);
  const size_t xb = (size_t)b * NC * NL;

  f32x4 acc[4] = {{0.f,0.f,0.f,0.f},{0.f,0.f,0.f,0.f},{0.f,0.f,0.f,0.f},{0.f,0.f,0.f,0.f}};

  for (int kc = 0; kc < 2; ++kc) {
#pragma unroll
    for (int i = 0; i < 4; ++i) {
      int id = t + i * 256;
      int r = id >> 4, u = (id & 15) << 2;
      int gr = m0 + r;
      int w_ = gr & 127, h = w_ >> 4, kk = w_ & 15;
      size_t rowoff = (((size_t)h * NB + b) * NDK + kk) * NC + kc * 64 + u;
      *(s16x4*)&Ah[r][u] = *(const s16x4*)&WpH[rowoff];
      *(s16x4*)&Al[r][u] = *(const s16x4*)&WpL[rowoff];
    }
    {
      int n = t & 63, kq = (t >> 6) * 16;
#pragma unroll
      for (int kk = 0; kk < 16; ++kk) {
        int k = kq + kk;
        size_t src = xb + (size_t)(kc * 64 + k) * NL + l0 + n;
        Xh[n][k] = XhB[src];
        Xl[n][k] = XlB[src];
      }
    }
    __syncthreads();
#pragma unroll
    for (int ks = 0; ks < 4; ++ks) {
      int ko = ks * 16 + 4 * g;
      s16x4 a_h = *(const s16x4*)&Ah[w * 16 + j16][ko];
      s16x4 a_l = *(const s16x4*)&Al[w * 16 + j16][ko];
#pragma unroll
      for (int nt = 0; nt < 4; ++nt) {
        s16x4 x_h = *(const s16x4*)&Xh[nt * 16 + j16][ko];
        s16x4 x_l = *(const s16x4*)&Xl[nt * 16 + j16][ko];
        acc[nt] = mfma_bf16_16x16x16(a_h, x_h, acc[nt]);
        acc[nt] = mfma_bf16_16x16x16(a_l, x_h, acc[nt]);
        acc[nt] = mfma_bf16_16x16x16(a_h, x_l, acc[nt]);
      }
    }
    __syncthreads();
  }

#pragma unroll
  for (int nt = 0; nt < 4; ++nt) {
    int n = l0 + nt * 16 + j16;
#pragma unroll
    for (int r = 0; r < 4; ++r) {
      int grow = m0 + w * 16 + 4 * g + r;
      int w_ = grow & 127, h = w_ >> 4, kk = w_ & 15;
      size_t idx = (((size_t)h * NB + b) * NDK + kk) * NL + n;
      float v = acc[nt][r];
      if (sel == 0) {
        float sv = v * 0.25f;
        unsigned short hi = f2bf(sv);
        qhw[idx] = hi; qlw[idx] = f2bf(sv - bf2f(hi));
      } else if (sel == 1) {
        unsigned short hi = f2bf(v);
        khw[idx] = hi; klw[idx] = f2bf(v - bf2f(hi));
      } else {
        vbw[idx] = f2bf(v);
      }
    }
  }
}

// ---------------- MFMA attention, fully LDS-resident (softmax over query axis i) ----------------
// grid: dim3(4, H*B); 256 thr = 4 waves; wave owns 2 j-tiles of 16. Zero barriers in loop.
// Output: head hi/lo bf16 (feeds Wo GEMM directly).
__global__ __launch_bounds__(256) void attn_kernel(const unsigned short* __restrict__ qh,
                                                   const unsigned short* __restrict__ ql,
                                                   const unsigned short* __restrict__ kh,
                                                   const unsigned short* __restrict__ kl,
                                                   const unsigned short* __restrict__ vb,
                                                   unsigned short* __restrict__ oh,
                                                   unsigned short* __restrict__ ol) {
  __shared__ unsigned short QtH[512][16], QtL[512][16];   // 16 KB each, [i][k]
  __shared__ unsigned short KtH[128][16], KtL[128][16];   // 4 KB each,  [j][k]
  __shared__ unsigned short Vt[16][520];                  // 16.25 KB,   [v][i] (+pad)
  const int t = threadIdx.x;
  const int lane = t & 63, w = t >> 6;
  const int g = lane >> 4, j16 = lane & 15;
  const int hb = blockIdx.y, jq = blockIdx.x;
  const int j0 = jq * 128;
  const int h = hb / NB, b = hb % NB;
  const size_t kb = (size_t)hb * NDK * NL;

  // stage Q hi/lo transposed [i][k] (coalesced over i)
  for (int n = 0; n < 32; ++n) {
    int e = n * 256 + t;
    int k = e >> 9, i = e & 511;
    QtH[i][k] = qh[kb + (size_t)k * NL + i];
    QtL[i][k] = ql[kb + (size_t)k * NL + i];
  }
  // stage V [v][i] (uint32 = 2 ushorts)
  for (int n = 0; n < 16; ++n) {
    int e = n * 256 + t;            // 4096 u32 units
    int v = e >> 8, i2 = e & 255;
    *(uint32_t*)&Vt[v][i2 * 2] = *(const uint32_t*)&vb[kb + (size_t)v * NL + i2 * 2];
  }
  // stage K quarter [j][k]
  for (int n = 0; n < 8; ++n) {
    int e = n * 256 + t;
    int k = e >> 7, j = e & 127;
    KtH[j][k] = kh[kb + (size_t)k * NL + j0 + j];
    KtL[j][k] = kl[kb + (size_t)k * NL + j0 + j];
  }
  __syncthreads();

  s16x4 KhiF[2], KloF[2];
#pragma unroll
  for (int q = 0; q < 2; ++q) {
    int jj = (w * 2 + q) * 16 + j16;
    KhiF[q] = *(const s16x4*)&KtH[jj][4 * g];
    KloF[q] = *(const s16x4*)&KtL[jj][4 * g];
  }

  float Mq[2] = {-INFINITY, -INFINITY};
  float lq[2] = {0.f, 0.f};
  f32x4 hC[2] = {{0.f, 0.f, 0.f, 0.f}, {0.f, 0.f, 0.f, 0.f}};

  for (int it = 0; it < 32; ++it) {
    s16x4 Qhi = *(const s16x4*)&QtH[it * 16 + j16][4 * g];
    s16x4 Qlo = *(const s16x4*)&QtL[it * 16 + j16][4 * g];
    s16x4 Vf  = *(const s16x4*)&Vt[j16][it * 16 + 4 * g];
#pragma unroll
    for (int q = 0; q < 2; ++q) {
      f32x4 S = {0.f, 0.f, 0.f, 0.f};
      S = mfma_bf16_16x16x16(Qhi, KhiF[q], S);
      S = mfma_bf16_16x16x16(Qlo, KhiF[q], S);
      S = mfma_bf16_16x16x16(Qhi, KloF[q], S);
      float tm = fmaxf(fmaxf(S[0], S[1]), fmaxf(S[2], S[3]));
      tm = fmaxf(tm, __shfl_xor(tm, 16));
      tm = fmaxf(tm, __shfl_xor(tm, 32));
      float Mn = fmaxf(Mq[q], tm);
      float corr = __expf(Mq[q] - Mn);
      Mq[q] = Mn;
      float p0 = __expf(S[0] - Mn), p1 = __expf(S[1] - Mn);
      float p2 = __expf(S[2] - Mn), p3 = __expf(S[3] - Mn);
      lq[q] = lq[q] * corr + ((p0 + p1) + (p2 + p3));
      hC[q] = hC[q] * corr;
      union { uint32_t u[2]; s16x4 s; } bp;
      bp.u[0] = (uint32_t)f2bf(p0) | ((uint32_t)f2bf(p1) << 16);
      bp.u[1] = (uint32_t)f2bf(p2) | ((uint32_t)f2bf(p3) << 16);
      hC[q] = mfma_bf16_16x16x16(Vf, bp.s, hC[q]);
    }
  }

#pragma unroll
  for (int q = 0; q < 2; ++q) {
    float l2 = lq[q] + __shfl_xor(lq[q], 16);
    float L  = l2 + __shfl_xor(l2, 32);
    float invL = 1.0f / L;
    int jglob = j0 + (w * 2 + q) * 16 + j16;
#pragma unroll
    for (int r = 0; r < 4; ++r) {
      float val = hC[q][r] * invL;
      size_t idx = ((size_t)b * NC + h * NDK + 4 * g + r) * NL + jglob;
      unsigned short hi = f2bf(val);
      oh[idx] = hi;
      ol[idx] = f2bf(val - bf2f(hi));
    }
  }
}

// ---------------- launch ----------------
extern "C" void kernel_launch(void* const* d_in, const int* in_sizes, int n_in,
                              void* d_out, int out_size, void* d_ws, size_t ws_size,
                              hipStream_t stream) {
  (void)in_sizes; (void)n_in; (void)out_size; (void)ws_size;
  const float* x    = (const float*)d_in[0];
  const float* dw_w = (const float*)d_in[1];
  const float* dw_b = (const float*)d_in[2];
  const float* pw_w = (const float*)d_in[3];
  const float* pw_b = (const float*)d_in[4];
  const float* Wq   = (const float*)d_in[5];
  const float* Wk   = (const float*)d_in[6];
  const float* Wv   = (const float*)d_in[7];
  const float* Wo   = (const float*)d_in[8];
  const float* W    = (const float*)d_in[9];
  float* out = (float*)d_out;

  const size_t N = NTOT;
  float* cur = (float*)d_ws;                      // N floats
  unsigned short* XhB = (unsigned short*)(cur + N);
  unsigned short* XlB = XhB + N;
  unsigned short* qh  = XlB + N;
  unsigned short* ql  = qh + N;
  unsigned short* kh  = ql + N;
  unsigned short* kl  = kh + N;
  unsigned short* vb  = kl + N;
  unsigned short* wsp = vb + N;                   // weight-split arena (PREP ushorts)

  uint32_t fk0[6], fk1[6];
  for (int i = 0; i < 6; ++i) {
    uint32_t a = 0u, bb = (uint32_t)i;
    tf2x32(0u, 7u, a, bb);
    fk0[i] = a; fk1[i] = bb;
  }

  prep_split_kernel<<<PREP_TOT / 256, 256, 0, stream>>>(pw_w, Wo, W, Wq, Wk, Wv, wsp);

  // conv block 0: pos-enc fused
  norm_dw_kernel<true, true><<<NB * NC, 64, 0, stream>>>(x, cur, XhB, XlB, dw_w, dw_b);
  gemm_mfma_kernel<0, false><<<dim3(8, 2, NB), 256, 0, stream>>>(
      wsp + oPwH, wsp + oPwL, XhB, XlB, cur, pw_b, cur, fk0[0], fk1[0]);
  for (int ci = 1; ci < 4; ++ci) {
    norm_dw_kernel<true, false><<<NB * NC, 64, 0, stream>>>(cur, nullptr, XhB, XlB,
                                                            dw_w + ci * NC * 7, dw_b + ci * NC);
    gemm_mfma_kernel<0, false><<<dim3(8, 2, NB), 256, 0, stream>>>(
        wsp + oPwH + (size_t)ci * NC * NC, wsp + oPwL + (size_t)ci * NC * NC,
        XhB, XlB, cur, pw_b + ci * NC, cur, fk0[ci], fk1[ci]);
  }

  norm_dw_kernel<false, false><<<NB * NC, 64, 0, stream>>>(cur, nullptr, XhB, XlB, nullptr, nullptr);
  qkv_mfma_kernel<<<dim3(8, 6, NB), 256, 0, stream>>>(wsp, XhB, XlB, qh, ql, kh, kl, vb);
  attn_kernel<<<dim3(4, NH * NB), 256, 0, stream>>>(qh, ql, kh, kl, vb, XhB, XlB);
  gemm_mfma_kernel<1, true><<<dim3(8, 2, NB), 256, 0, stream>>>(
      wsp + oWoH, wsp + oWoL, XhB, XlB, cur, nullptr, cur, fk0[4], fk1[4]);

  norm_dw_kernel<false, false><<<NB * NC, 64, 0, stream>>>(cur, nullptr, XhB, XlB, nullptr, nullptr);
  gemm_mfma_kernel<2, true><<<dim3(8, 2, NB), 256, 0, stream>>>(
      wsp + oWH, wsp + oWL, XhB, XlB, out, nullptr, cur, fk0[5], fk1[5]);
}